// Round 6
// baseline (728.280 us; speedup 1.0000x reference)
//
#include <hip/hip_runtime.h>
#include <hip/hip_bf16.h>

typedef float  f32x4  __attribute__((ext_vector_type(4)));
typedef short  s16x8  __attribute__((ext_vector_type(8)));
typedef unsigned short u16x4 __attribute__((ext_vector_type(4)));
typedef unsigned short u16x8 __attribute__((ext_vector_type(8)));

constexpr int N_NODES = 100000;
constexpr int N_EDGES = 3200000;
constexpr int D = 256;

// ---- workspace layout (bytes) ----
constexpr size_t OFF_H        = 0;                       // bf16 H: 51,200,000
constexpr size_t OFF_COUNTS   = 51200000;
constexpr size_t OFF_ROWSTART = 51600000;
constexpr size_t OFF_BSUM     = 52000256;
constexpr size_t OFF_BOFF     = 52000768;
constexpr size_t OFF_WT       = 52001280;                // bf16 W^T: 131,072
constexpr size_t OFF_PACKED   = 52132352;                // 3.2M int2 = 25.6 MB
constexpr int SCAN_BLK = 98;

__device__ inline unsigned short f2bf(float f) {
  __hip_bfloat16 h = __float2bfloat16(f);                // RNE
  return *reinterpret_cast<unsigned short*>(&h);
}

// ---------------------------------------------------------------------------
// W[256][256] fp32 -> Wt[j][k] bf16 (transpose + cast)
// ---------------------------------------------------------------------------
__global__ __launch_bounds__(256)
void wt_cast(const float* __restrict__ W, unsigned short* __restrict__ Wt) {
  __shared__ float Ws[32][33];
  const int bx = blockIdx.x & 7, by = blockIdx.x >> 3;
  const int k0 = by * 32, j0 = bx * 32;
  const int t = threadIdx.x;
  const int tr = t >> 3, tc = (t & 7) * 4;
  f32x4 v = *reinterpret_cast<const f32x4*>(W + (size_t)(k0 + tr) * D + j0 + tc);
#pragma unroll
  for (int i = 0; i < 4; ++i) Ws[tr][tc + i] = v[i];
  __syncthreads();
  u16x4 o = { f2bf(Ws[tc + 0][tr]), f2bf(Ws[tc + 1][tr]),
              f2bf(Ws[tc + 2][tr]), f2bf(Ws[tc + 3][tr]) };
  *reinterpret_cast<u16x4*>(Wt + (size_t)(j0 + tr) * D + k0 + tc) = o;
}

// ---------------------------------------------------------------------------
// GEMM (bf16 MFMA): Hb = bf16(X @ W). BM=128, BN=256, BK=64.
// LDS rows 128 B; swizzle byte ^= ((row&7)<<4); write 8/16B, read 16B granule.
// ---------------------------------------------------------------------------
__global__ __launch_bounds__(256, 2)
void gemm_mfma(const float* __restrict__ X, const unsigned short* __restrict__ Wt,
               unsigned short* __restrict__ Hb) {
  __shared__ char As[128 * 128];   // 128 rows x 64 bf16
  __shared__ char Bs[256 * 128];   // 256 cols x 64 bf16

  const int t    = threadIdx.x;
  const int l    = t & 63;
  const int w    = t >> 6;
  const int row0 = blockIdx.x * 128;
  const int m_base = w * 32;

  f32x4 acc[2][16];
#pragma unroll
  for (int mi = 0; mi < 2; ++mi)
#pragma unroll
    for (int ni = 0; ni < 16; ++ni) acc[mi][ni] = (f32x4){0.f, 0.f, 0.f, 0.f};

  for (int kc = 0; kc < D; kc += 64) {
    // stage A: 128 rows x 64 k, fp32 -> bf16
#pragma unroll
    for (int i = 0; i < 8; ++i) {
      const int lin = i * 256 + t;
      const int r = lin >> 4, g = lin & 15;
      int row = row0 + r; if (row >= N_NODES) row = N_NODES - 1;
      f32x4 v = *reinterpret_cast<const f32x4*>(X + (size_t)row * D + kc + g * 4);
      u16x4 o = { f2bf(v[0]), f2bf(v[1]), f2bf(v[2]), f2bf(v[3]) };
      *reinterpret_cast<u16x4*>(As + r * 128 + ((g * 8) ^ ((r & 7) << 4))) = o;
    }
    // stage B: 256 cols x 64 k from Wt (bf16, contiguous)
#pragma unroll
    for (int i = 0; i < 8; ++i) {
      const int lin = i * 256 + t;
      const int j = lin >> 3, g = lin & 7;
      u16x8 v = *reinterpret_cast<const u16x8*>(Wt + (size_t)j * D + kc + g * 8);
      *reinterpret_cast<u16x8*>(Bs + j * 128 + ((g * 16) ^ ((j & 7) << 4))) = v;
    }
    __syncthreads();

    s16x8 a[2][2];
#pragma unroll
    for (int mi = 0; mi < 2; ++mi)
#pragma unroll
      for (int kk = 0; kk < 2; ++kk) {
        const int r = m_base + mi * 16 + (l & 15);
        a[mi][kk] = *reinterpret_cast<const s16x8*>(
            As + r * 128 + ((kk * 64 + (l >> 4) * 16) ^ ((r & 7) << 4)));
      }
#pragma unroll
    for (int ni = 0; ni < 16; ++ni) {
      const int j = ni * 16 + (l & 15);
#pragma unroll
      for (int kk = 0; kk < 2; ++kk) {
        s16x8 b = *reinterpret_cast<const s16x8*>(
            Bs + j * 128 + ((kk * 64 + (l >> 4) * 16) ^ ((j & 7) << 4)));
        acc[0][ni] = __builtin_amdgcn_mfma_f32_16x16x32_bf16(a[0][kk], b, acc[0][ni], 0, 0, 0);
        acc[1][ni] = __builtin_amdgcn_mfma_f32_16x16x32_bf16(a[1][kk], b, acc[1][ni], 0, 0, 0);
      }
    }
    __syncthreads();
  }

  // epilogue: col = ni*16 + (l&15), row = m_base + mi*16 + (l>>4)*4 + r
#pragma unroll
  for (int mi = 0; mi < 2; ++mi)
#pragma unroll
    for (int ni = 0; ni < 16; ++ni)
#pragma unroll
      for (int r = 0; r < 4; ++r) {
        const int row = row0 + m_base + mi * 16 + ((l >> 4) << 2) + r;
        if (row < N_NODES)
          Hb[(size_t)row * D + ni * 16 + (l & 15)] = f2bf(acc[mi][ni][r]);
      }
}

// ---------------------------------------------------------------------------
// Counting-sort CSR build (edge reads vectorized x4)
// ---------------------------------------------------------------------------
__global__ __launch_bounds__(256)
void hist_rows(const int* __restrict__ arow, int* __restrict__ counts) {
  const int4* a4 = reinterpret_cast<const int4*>(arow);
  const int n4 = N_EDGES / 4;
  for (int i = blockIdx.x * 256 + threadIdx.x; i < n4; i += gridDim.x * 256) {
    const int4 r = a4[i];
    atomicAdd(&counts[r.x], 1);
    atomicAdd(&counts[r.y], 1);
    atomicAdd(&counts[r.z], 1);
    atomicAdd(&counts[r.w], 1);
  }
}

__global__ __launch_bounds__(256)
void scan_block_sums(const int* __restrict__ counts, int* __restrict__ bsum) {
  __shared__ int sd[256];
  const int b = blockIdx.x, t = threadIdx.x;
  const int base = b * 1024 + t * 4;
  int s = 0;
#pragma unroll
  for (int j = 0; j < 4; ++j) { int idx = base + j; if (idx < N_NODES) s += counts[idx]; }
  sd[t] = s; __syncthreads();
  for (int off = 128; off > 0; off >>= 1) {
    if (t < off) sd[t] += sd[t + off];
    __syncthreads();
  }
  if (t == 0) bsum[b] = sd[0];
}

__global__ __launch_bounds__(128)
void scan_bsums(const int* __restrict__ bsum, int* __restrict__ boff,
                int* __restrict__ row_start) {
  __shared__ int sd[128];
  const int t = threadIdx.x;
  int v = (t < SCAN_BLK) ? bsum[t] : 0;
  sd[t] = v; __syncthreads();
  for (int off = 1; off < 128; off <<= 1) {
    int x = (t >= off) ? sd[t - off] : 0;
    __syncthreads();
    sd[t] += x;
    __syncthreads();
  }
  if (t < SCAN_BLK) boff[t] = sd[t] - v;
  if (t == 0) row_start[N_NODES] = N_EDGES;
}

__global__ __launch_bounds__(256)
void scan_write(const int* __restrict__ counts, const int* __restrict__ boff,
                int* __restrict__ row_start) {
  __shared__ int sd[256];
  const int b = blockIdx.x, t = threadIdx.x;
  const int base = b * 1024 + t * 4;
  int v[4];
#pragma unroll
  for (int j = 0; j < 4; ++j) v[j] = (base + j < N_NODES) ? counts[base + j] : 0;
  int l0 = 0, l1 = v[0], l2 = v[0] + v[1], l3 = v[0] + v[1] + v[2];
  int s = l3 + v[3];
  sd[t] = s; __syncthreads();
  for (int off = 1; off < 256; off <<= 1) {
    int x = (t >= off) ? sd[t - off] : 0;
    __syncthreads();
    sd[t] += x;
    __syncthreads();
  }
  const int o = boff[b] + sd[t] - s;
  if (base + 0 < N_NODES) row_start[base + 0] = o + l0;
  if (base + 1 < N_NODES) row_start[base + 1] = o + l1;
  if (base + 2 < N_NODES) row_start[base + 2] = o + l2;
  if (base + 3 < N_NODES) row_start[base + 3] = o + l3;
}

__global__ __launch_bounds__(256)
void bin_edges(const int* __restrict__ arow, const int* __restrict__ acol,
               const float* __restrict__ aval, int* __restrict__ counts,
               const int* __restrict__ row_start, int2* __restrict__ packed) {
  const int4*   r4 = reinterpret_cast<const int4*>(arow);
  const int4*   c4 = reinterpret_cast<const int4*>(acol);
  const float4* v4 = reinterpret_cast<const float4*>(aval);
  const int n4 = N_EDGES / 4;
  for (int i = blockIdx.x * 256 + threadIdx.x; i < n4; i += gridDim.x * 256) {
    const int4 r = r4[i]; const int4 c = c4[i]; const float4 v = v4[i];
    int o;
    o = atomicSub(&counts[r.x], 1); packed[row_start[r.x] + o - 1] = make_int2(c.x, __float_as_int(v.x));
    o = atomicSub(&counts[r.y], 1); packed[row_start[r.y] + o - 1] = make_int2(c.y, __float_as_int(v.y));
    o = atomicSub(&counts[r.z], 1); packed[row_start[r.z] + o - 1] = make_int2(c.z, __float_as_int(v.z));
    o = atomicSub(&counts[r.w], 1); packed[row_start[r.w] + o - 1] = make_int2(c.w, __float_as_int(v.w));
  }
}

// ---------------------------------------------------------------------------
// Segmented reduce over bf16 H: wave per row, lane l owns dims 4l..4l+3.
// Unroll 8 for deep ILP on the random gathers.
// ---------------------------------------------------------------------------
__device__ inline f32x4 bf4_to_f4(u16x4 h) {
  f32x4 r;
#pragma unroll
  for (int j = 0; j < 4; ++j) r[j] = __uint_as_float(((unsigned)h[j]) << 16);
  return r;
}

__global__ __launch_bounds__(256)
void row_reduce(const int* __restrict__ row_start, const int2* __restrict__ packed,
                const unsigned short* __restrict__ Hb, const float* __restrict__ bias,
                float* __restrict__ out) {
  const int row = blockIdx.x * 4 + (threadIdx.x >> 6);
  const int l = threadIdx.x & 63;
  if (row >= N_NODES) return;
  const int s = row_start[row];
  const int e = row_start[row + 1];

  f32x4 acc[8];
#pragma unroll
  for (int u = 0; u < 8; ++u) acc[u] = (f32x4){0.f, 0.f, 0.f, 0.f};

  int i = s;
  for (; i + 8 <= e; i += 8) {
    int2 p[8];
#pragma unroll
    for (int u = 0; u < 8; ++u) p[u] = packed[i + u];
#pragma unroll
    for (int u = 0; u < 8; ++u) {
      const f32x4 h = bf4_to_f4(
          *reinterpret_cast<const u16x4*>(Hb + (size_t)p[u].x * D + l * 4));
      const float v = __int_as_float(p[u].y);
#pragma unroll
      for (int j = 0; j < 4; ++j) acc[u][j] += v * h[j];
    }
  }
  for (; i + 2 <= e; i += 2) {
    const int2 p0 = packed[i], p1 = packed[i + 1];
    const f32x4 h0 = bf4_to_f4(*reinterpret_cast<const u16x4*>(Hb + (size_t)p0.x * D + l * 4));
    const f32x4 h1 = bf4_to_f4(*reinterpret_cast<const u16x4*>(Hb + (size_t)p1.x * D + l * 4));
    const float v0 = __int_as_float(p0.y), v1 = __int_as_float(p1.y);
#pragma unroll
    for (int j = 0; j < 4; ++j) { acc[0][j] += v0 * h0[j]; acc[1][j] += v1 * h1[j]; }
  }
  if (i < e) {
    const int2 p = packed[i];
    const f32x4 h = bf4_to_f4(*reinterpret_cast<const u16x4*>(Hb + (size_t)p.x * D + l * 4));
    const float v = __int_as_float(p.y);
#pragma unroll
    for (int j = 0; j < 4; ++j) acc[2][j] += v * h[j];
  }

  const f32x4 b = *reinterpret_cast<const f32x4*>(bias + l * 4);
  f32x4 o;
#pragma unroll
  for (int j = 0; j < 4; ++j)
    o[j] = ((acc[0][j] + acc[1][j]) + (acc[2][j] + acc[3][j])) +
           ((acc[4][j] + acc[5][j]) + (acc[6][j] + acc[7][j])) + b[j];
  *reinterpret_cast<f32x4*>(out + (size_t)row * D + l * 4) = o;
}

// ---------------------------------------------------------------------------
extern "C" void kernel_launch(void* const* d_in, const int* in_sizes, int n_in,
                              void* d_out, int out_size, void* d_ws, size_t ws_size,
                              hipStream_t stream) {
  const float* X    = (const float*)d_in[0];
  const int*   arow = (const int*)  d_in[1];
  const int*   acol = (const int*)  d_in[2];
  const float* aval = (const float*)d_in[3];
  const float* W    = (const float*)d_in[4];
  const float* bias = (const float*)d_in[5];
  float* out = (float*)d_out;

  char* ws = (char*)d_ws;
  unsigned short* Hb        = (unsigned short*)(ws + OFF_H);
  int*            counts    = (int*)  (ws + OFF_COUNTS);
  int*            row_start = (int*)  (ws + OFF_ROWSTART);
  int*            bsum      = (int*)  (ws + OFF_BSUM);
  int*            boff      = (int*)  (ws + OFF_BOFF);
  unsigned short* Wt        = (unsigned short*)(ws + OFF_WT);
  int2*           packed    = (int2*) (ws + OFF_PACKED);

  // 1) W -> Wt (bf16, transposed); Hb = bf16(X @ W) via MFMA
  wt_cast<<<64, 256, 0, stream>>>(W, Wt);
  gemm_mfma<<<(N_NODES + 127) / 128, 256, 0, stream>>>(X, Wt, Hb);

  // 2) CSR build
  hipMemsetAsync(counts, 0, N_NODES * sizeof(int), stream);
  hist_rows<<<2048, 256, 0, stream>>>(arow, counts);
  scan_block_sums<<<SCAN_BLK, 256, 0, stream>>>(counts, bsum);
  scan_bsums<<<1, 128, 0, stream>>>(bsum, boff, row_start);
  scan_write<<<SCAN_BLK, 256, 0, stream>>>(counts, boff, row_start);
  bin_edges<<<2048, 256, 0, stream>>>(arow, acol, aval, counts, row_start, packed);

  // 3) segmented reduce (bias folded)
  row_reduce<<<(N_NODES + 3) / 4, 256, 0, stream>>>(row_start, packed, Hb, bias, out);
}